// Round 2
// baseline (187.090 us; speedup 1.0000x reference)
//
#include <hip/hip_runtime.h>

// 5x5 mean filter, count_include_pad=False, on [32,3,512,512] fp32.
// Batch-strip design: one wave per (plane, 8-row strip); lane owns 8 cols.
// All 12 input rows' loads (24x float4) are issued before any use -> deep
// memory-level parallelism instead of a latency-exposed rolling pipeline.

#define HH 512
#define WW 512
#define NPLANES 96              // B*C = 32*3
#define SROWS 8                 // output rows per wave
#define STRIPS (HH / SROWS)     // 64
#define NROWS (SROWS + 4)       // 12 input rows incl. vertical halo

__global__ __launch_bounds__(64, 2) void box5_kernel(const float* __restrict__ x,
                                                     float* __restrict__ out) {
    const int lane = threadIdx.x;            // 0..63
    const int gid = blockIdx.x;              // one wave per block
    const int plane = gid / STRIPS;
    const int strip = gid % STRIPS;
    const int y0 = strip * SROWS;

    const float* px = x + (size_t)plane * (HH * WW);
    float* pout = out + (size_t)plane * (HH * WW);
    const int w0 = lane * 8;

    // ---- Issue ALL loads for the strip up front (24 independent 16B loads).
    // Vertical OOB rows are clamped (harmless read) and masked to zero later,
    // keeping lanes converged and loads unconditional.
    float4 ra[NROWS], rb[NROWS];
#pragma unroll
    for (int r = 0; r < NROWS; ++r) {
        int y = y0 - 2 + r;
        int yc = min(max(y, 0), HH - 1);
        const float* p = px + (size_t)yc * WW + w0;
        ra[r] = *(const float4*)(p);
        rb[r] = *(const float4*)(p + 4);
    }

    // ---- Horizontal 5-tap sliding sums per row (masked for OOB rows).
    float hs[NROWS][8];
#pragma unroll
    for (int r = 0; r < NROWS; ++r) {
        const int y = y0 - 2 + r;
        const float mask = (y >= 0 && y < HH) ? 1.0f : 0.0f;

        const float xv0 = ra[r].x, xv1 = ra[r].y, xv2 = ra[r].z, xv3 = ra[r].w;
        const float xv4 = rb[r].x, xv5 = rb[r].y, xv6 = rb[r].z, xv7 = rb[r].w;

        float xm2 = __shfl_up(xv6, 1);
        float xm1 = __shfl_up(xv7, 1);
        float xp1 = __shfl_down(xv0, 1);
        float xp2 = __shfl_down(xv1, 1);
        if (lane == 0)  { xm2 = 0.0f; xm1 = 0.0f; }
        if (lane == 63) { xp1 = 0.0f; xp2 = 0.0f; }

        float t = xm2 + xm1 + xv0 + xv1 + xv2;
        hs[r][0] = t;
        t += xv3 - xm2; hs[r][1] = t;
        t += xv4 - xm1; hs[r][2] = t;
        t += xv5 - xv0; hs[r][3] = t;
        t += xv6 - xv1; hs[r][4] = t;
        t += xv7 - xv2; hs[r][5] = t;
        t += xp1 - xv3; hs[r][6] = t;
        t += xp2 - xv4; hs[r][7] = t;
#pragma unroll
        for (int j = 0; j < 8; ++j) hs[r][j] *= mask;
    }

    // ---- Per-column inverse counts (boundary-aware), constant per thread.
    float inv_cw[8];
#pragma unroll
    for (int j = 0; j < 8; ++j) {
        int w = w0 + j;
        int cw = min(w + 2, WW - 1) - max(w - 2, 0) + 1;
        inv_cw[j] = 1.0f / (float)cw;
    }

    // ---- Vertical 5-row sums + separable normalization, store 8 rows.
#pragma unroll
    for (int o = 0; o < SROWS; ++o) {
        const int y_out = y0 + o;
        const int ch = min(y_out + 2, HH - 1) - max(y_out - 2, 0) + 1;
        const float inv_ch = 1.0f / (float)ch;   // wave-uniform

        float ov[8];
#pragma unroll
        for (int j = 0; j < 8; ++j) {
            float vs = hs[o][j] + hs[o + 1][j] + hs[o + 2][j] + hs[o + 3][j] + hs[o + 4][j];
            ov[j] = vs * (inv_cw[j] * inv_ch);
        }
        float* po = pout + (size_t)y_out * WW + w0;
        *(float4*)(po)     = make_float4(ov[0], ov[1], ov[2], ov[3]);
        *(float4*)(po + 4) = make_float4(ov[4], ov[5], ov[6], ov[7]);
    }
}

extern "C" void kernel_launch(void* const* d_in, const int* in_sizes, int n_in,
                              void* d_out, int out_size, void* d_ws, size_t ws_size,
                              hipStream_t stream) {
    const float* x = (const float*)d_in[0];
    float* out = (float*)d_out;
    // k_size (d_in[1]) is fixed at 5 per the reference; hard-coded above.
    dim3 grid(NPLANES * STRIPS);
    box5_kernel<<<grid, 64, 0, stream>>>(x, out);
}

// Round 4
// 177.978 us; speedup vs baseline: 1.0512x; 1.0512x over previous
//
#include <hip/hip_runtime.h>

// 5x5 mean filter, count_include_pad=False, on [32,3,512,512] fp32.
// LDS-staged: global_load_lds (16B, no VGPR dest) keeps all staging loads in
// flight -> real MLP. 256-thread block stages a 20-row tile (16 out rows + 4
// halo) into 40KB LDS; each of 4 waves computes 4 output rows full-width.

#define HH 512
#define WW 512
#define NPLANES 96
#define SROWS 16                 // output rows per block
#define STRIPS (HH / SROWS)      // 32
#define TROWS (SROWS + 4)        // 20 input rows in LDS
#define NCHUNK (TROWS * 2)       // 40 x 1KB staging ops per block

typedef const __attribute__((address_space(1))) void* gas_ptr;
typedef __attribute__((address_space(3))) void* las_ptr;

__global__ __launch_bounds__(256, 4) void box5_kernel(const float* __restrict__ x,
                                                      float* __restrict__ out) {
    __shared__ float smem[TROWS * WW];   // 40960 B

    const int tid  = threadIdx.x;
    const int lane = tid & 63;
    const int wv   = tid >> 6;           // 0..3
    const int gid  = blockIdx.x;
    const int plane = gid / STRIPS;
    const int strip = gid % STRIPS;
    const int y0 = strip * SROWS;

    const float* px = x + (size_t)plane * (HH * WW);
    float* pout = out + (size_t)plane * (HH * WW);

    // ---- Stage 20 rows into LDS. 10 chunks/wave, each 64 lanes x 16B = 1KB.
    // LDS dest is wave-uniform base (HW adds lane*16); global src is per-lane.
    // Vertical OOB rows are clamped at the source and masked to zero later.
#pragma unroll
    for (int i = 0; i < NCHUNK / 4; ++i) {
        const int idx  = wv * (NCHUNK / 4) + i;
        const int r    = idx >> 1;
        const int half = idx & 1;
        const int yc = min(max(y0 - 2 + r, 0), HH - 1);
        const float* gsrc = px + (size_t)yc * WW + half * (WW / 2) + lane * 4;
        __builtin_amdgcn_global_load_lds((gas_ptr)gsrc,
                                         (las_ptr)&smem[r * WW + half * (WW / 2)],
                                         16, 0, 0);
    }
    __syncthreads();   // drains vmcnt -> tile visible

    const int w0 = lane * 8;

    // Per-column inverse counts (boundary-aware), constant per thread.
    float inv_cw[8];
#pragma unroll
    for (int j = 0; j < 8; ++j) {
        int w = w0 + j;
        int cw = min(w + 2, WW - 1) - max(w - 2, 0) + 1;
        inv_cw[j] = 1.0f / (float)cw;
    }

    // ---- Horizontal 5-tap sliding sums for the 8 tile rows this wave needs.
    // Wave wv produces output rows y0+4*wv .. +3, consuming tile rows
    // lr = 4*wv .. 4*wv+7.
    float hs[8][8];
#pragma unroll
    for (int q = 0; q < 8; ++q) {
        const int lr = wv * 4 + q;
        const int y  = y0 - 2 + lr;
        const float mask = (y >= 0 && y < HH) ? 1.0f : 0.0f;

        const float4 a = *(const float4*)&smem[lr * WW + w0];
        const float4 b = *(const float4*)&smem[lr * WW + w0 + 4];
        const float xv0 = a.x, xv1 = a.y, xv2 = a.z, xv3 = a.w;
        const float xv4 = b.x, xv5 = b.y, xv6 = b.z, xv7 = b.w;

        float xm2 = __shfl_up(xv6, 1);
        float xm1 = __shfl_up(xv7, 1);
        float xp1 = __shfl_down(xv0, 1);
        float xp2 = __shfl_down(xv1, 1);
        if (lane == 0)  { xm2 = 0.0f; xm1 = 0.0f; }
        if (lane == 63) { xp1 = 0.0f; xp2 = 0.0f; }

        float t = xm2 + xm1 + xv0 + xv1 + xv2;
        hs[q][0] = t;
        t += xv3 - xm2; hs[q][1] = t;
        t += xv4 - xm1; hs[q][2] = t;
        t += xv5 - xv0; hs[q][3] = t;
        t += xv6 - xv1; hs[q][4] = t;
        t += xv7 - xv2; hs[q][5] = t;
        t += xp1 - xv3; hs[q][6] = t;
        t += xp2 - xv4; hs[q][7] = t;
#pragma unroll
        for (int j = 0; j < 8; ++j) hs[q][j] *= mask;
    }

    // ---- Vertical 5-row sums + separable normalization; store 4 rows.
#pragma unroll
    for (int o = 0; o < 4; ++o) {
        const int y_out = y0 + wv * 4 + o;
        const int ch = min(y_out + 2, HH - 1) - max(y_out - 2, 0) + 1;
        const float inv_ch = 1.0f / (float)ch;   // wave-uniform

        float ov[8];
#pragma unroll
        for (int j = 0; j < 8; ++j) {
            float vs = hs[o][j] + hs[o + 1][j] + hs[o + 2][j] + hs[o + 3][j] + hs[o + 4][j];
            ov[j] = vs * (inv_cw[j] * inv_ch);
        }
        float* po = pout + (size_t)y_out * WW + w0;
        *(float4*)(po)     = make_float4(ov[0], ov[1], ov[2], ov[3]);
        *(float4*)(po + 4) = make_float4(ov[4], ov[5], ov[6], ov[7]);
    }
}

extern "C" void kernel_launch(void* const* d_in, const int* in_sizes, int n_in,
                              void* d_out, int out_size, void* d_ws, size_t ws_size,
                              hipStream_t stream) {
    const float* x = (const float*)d_in[0];
    float* out = (float*)d_out;
    // k_size (d_in[1]) is fixed at 5 per the reference; hard-coded above.
    dim3 grid(NPLANES * STRIPS);   // 3072 blocks
    box5_kernel<<<grid, 256, 0, stream>>>(x, out);
}